// Round 7
// baseline (423.681 us; speedup 1.0000x reference)
//
#include <hip/hip_runtime.h>
#include <hip/hip_bf16.h>
#include <stdint.h>

// RPGNN: threefry ranks -> CSR -> fp8 gather-agg -> persistent-B pipelined
// bf16 MFMA GEMMs -> y=h@W2 (fp8 out) -> fused fp8-gather+relu+segment-pool.
// Layer2 uses linearity: (h + sum_N h) @ W2 = y_v + sum_N y_u, y = h@W2.

#define D_IN   128
#define KRAW   138
#define K1     160   // A row stride, layer 1
#define B1ROW  192   // B padded row (elems) layer 1
#define HDIM   256
#define NGRAPH 2000
#define MAXS   6

typedef __bf16 bf16x8 __attribute__((ext_vector_type(8)));
typedef float  f32x4  __attribute__((ext_vector_type(4)));

__device__ __forceinline__ unsigned short f2b(float f) {
  __hip_bfloat16 h = __float2bfloat16(f);
  return __builtin_bit_cast(unsigned short, h);
}
__device__ __forceinline__ float blo(unsigned p) { return __uint_as_float(p << 16); }
__device__ __forceinline__ float bhi(unsigned p) { return __uint_as_float(p & 0xffff0000u); }

// ---- manual OCP e4m3 encode/decode (subnormals flushed at encode) ----
__device__ __forceinline__ unsigned e8(float f) {
  unsigned u = __float_as_uint(f);
  unsigned s = (u >> 24) & 0x80u;
  float a = fabsf(f);
  if (!(a >= 0.015625f)) return s;           // flush tiny (and NaN) to +-0
  a = fminf(a, 448.f);
  unsigned b = __float_as_uint(a);
  b += 0x0007FFFFu + ((b >> 20) & 1u);       // RNE to 3 mantissa bits
  unsigned e = (b >> 23) - 120u;             // (exp-127)+7
  unsigned m = (b >> 20) & 7u;
  return s | (e << 3) | m;
}
__device__ __forceinline__ float d8(unsigned byte) {
  unsigned m = byte & 0x7fu;
  unsigned bits = (0x3C000000u + (m << 20)) | ((byte & 0x80u) << 24);
  return m ? __uint_as_float(bits) : 0.f;
}

__device__ __forceinline__ void glds16(const unsigned short* g, unsigned short* l) {
  __builtin_amdgcn_global_load_lds(
      (const __attribute__((address_space(1))) unsigned int*)g,
      (__attribute__((address_space(3))) unsigned int*)l, 16, 0, 0);
}

// ---------------- threefry2x32 (bit-exact JAX replica) ----------------
__device__ __forceinline__ unsigned rotl32(unsigned x, int r) {
  return (x << r) | (x >> (32 - r));
}
__device__ __forceinline__ void threefry2x32(unsigned k0, unsigned k1,
                                             unsigned x0, unsigned x1,
                                             unsigned& o0, unsigned& o1) {
  unsigned ks2 = k0 ^ k1 ^ 0x1BD11BDAu;
  unsigned ks[3] = {k0, k1, ks2};
  x0 += ks[0]; x1 += ks[1];
  const int rotA[4] = {13, 15, 26, 6};
  const int rotB[4] = {17, 29, 16, 24};
#pragma unroll
  for (int i = 0; i < 5; ++i) {
    const int* rot = (i & 1) ? rotB : rotA;
#pragma unroll
    for (int j = 0; j < 4; ++j) {
      x0 += x1; x1 = rotl32(x1, rot[j]); x1 ^= x0;
    }
    x0 += ks[(i + 1) % 3];
    x1 += ks[(i + 2) % 3] + (unsigned)(i + 1);
  }
  o0 = x0; o1 = x1;
}

__global__ void k_prep2(const int* __restrict__ bids, const int* __restrict__ dst,
                        float* __restrict__ r, int* __restrict__ start,
                        int* __restrict__ cnt, int* __restrict__ deg, int N, int E) {
  int i = blockIdx.x * blockDim.x + threadIdx.x;
  if (i < E) atomicAdd(&deg[dst[i]], 1);
  if (i >= N) return;
  int half = N >> 1;
  if (i < half) {
    unsigned fk0, fk1;
    threefry2x32(0u, 42u, 0u, 0u, fk0, fk1);          // fold_in(key(42), 0)
    unsigned b0, b1v;
    threefry2x32(fk0, fk1, (unsigned)i, (unsigned)(i + half), b0, b1v);
    r[i]        = __uint_as_float((b0  >> 9) | 0x3f800000u) - 1.0f;
    r[i + half] = __uint_as_float((b1v >> 9) | 0x3f800000u) - 1.0f;
  }
  int g = bids[i];
  if (i == 0 || bids[i - 1] != g) start[g] = i;
  atomicAdd(&cnt[g], 1);
}

// rank within graph under key = float(g)+r, stable tie-break on index
__global__ void k_rank(const float* __restrict__ r, const int* __restrict__ start,
                       const int* __restrict__ cnt, int* __restrict__ ids) {
  int g = blockIdx.x;
  int st = start[g], n = cnt[g];
  if (n <= 0) return;
  float gf = (float)g;
  for (int t = threadIdx.x; t < n; t += blockDim.x) {
    int v = st + t;
    float kv = gf + r[v];
    int c = 0;
    for (int u0 = 0; u0 < n; ++u0) {
      int u = st + u0;
      float ku = gf + r[u];
      c += (int)((ku < kv) | ((ku == kv) & (u < v)));
    }
    ids[v] = c % 10;
  }
}

// ---------------- CSR build ----------------
__global__ void k_scan1(const int* __restrict__ deg, int* __restrict__ rowptr,
                        int* __restrict__ bsum, int N) {
  __shared__ int buf[256];
  int tid = threadIdx.x;
  int i = blockIdx.x * 256 + tid;
  int v = (i < N) ? deg[i] : 0;
  buf[tid] = v;
  __syncthreads();
  for (int off = 1; off < 256; off <<= 1) {
    int t = (tid >= off) ? buf[tid - off] : 0;
    __syncthreads();
    buf[tid] += t;
    __syncthreads();
  }
  if (i < N) rowptr[i] = buf[tid] - v;
  if (tid == 255) bsum[blockIdx.x] = buf[255];
}

__global__ void k_scan2(int* __restrict__ bsum, int nb) {
  __shared__ int buf[512];
  int tid = threadIdx.x;
  int v = (tid < nb) ? bsum[tid] : 0;
  buf[tid] = v;
  __syncthreads();
  for (int off = 1; off < 512; off <<= 1) {
    int t = (tid >= off) ? buf[tid - off] : 0;
    __syncthreads();
    buf[tid] += t;
    __syncthreads();
  }
  if (tid < nb) bsum[tid] = buf[tid] - v;
}

__global__ void k_scan3(int* __restrict__ rowptr, const int* __restrict__ bsum,
                        int N, int E) {
  int i = blockIdx.x * 256 + threadIdx.x;
  if (i < N) rowptr[i] += bsum[blockIdx.x];
  if (i == 0) rowptr[N] = E;
}

__global__ void k_scatter(const int* __restrict__ src, const int* __restrict__ dst,
                          const int* __restrict__ rowptr, int* __restrict__ fill,
                          int* __restrict__ csr, int E) {
  int e = blockIdx.x * 256 + threadIdx.x;
  if (e >= E) return;
  int d = dst[e];
  int pos = rowptr[d] + atomicAdd(&fill[d], 1);
  csr[pos] = src[e];
}

// ---------------- x->fp8 + weight prep (merged) ----------------
__global__ void k_pre(const float* __restrict__ x, const float* __restrict__ W1,
                      const float* __restrict__ W2, unsigned char* __restrict__ x8,
                      unsigned short* __restrict__ Wpt, unsigned short* __restrict__ W2t,
                      int n8, int xbb) {
  int bid = blockIdx.x;
  int tid = threadIdx.x;
  if (bid < xbb) {
    int i = bid * 256 + tid;
    if (i >= n8) return;
    const float4* xp = reinterpret_cast<const float4*>(x) + (size_t)i * 2;
    float4 v0 = xp[0], v1 = xp[1];
    uint2 o;
    o.x = e8(v0.x) | (e8(v0.y) << 8) | (e8(v0.z) << 16) | (e8(v0.w) << 24);
    o.y = e8(v1.x) | (e8(v1.y) << 8) | (e8(v1.z) << 16) | (e8(v1.w) << 24);
    reinterpret_cast<uint2*>(x8)[i] = o;
  } else {
    int j = (bid - xbb) * 256 + tid;
    if (j < HDIM * B1ROW) {
      int n = j / B1ROW, k = j % B1ROW;
      Wpt[j] = f2b(k < KRAW ? W1[k * HDIM + n] : 0.f);
    } else {
      int j2 = j - HDIM * B1ROW;
      if (j2 < HDIM * HDIM) {
        int n = j2 >> 8, k = j2 & 255;
        W2t[j2] = f2b(W2[k * HDIM + n]);
      }
    }
  }
}

// ---------------- layer-1 aggregation (wave/node, fp8 gather) ----------------
__global__ void k_agg1(const unsigned char* __restrict__ x8, const int* __restrict__ ids,
                       const int* __restrict__ rowptr, const int* __restrict__ csr,
                       unsigned short* __restrict__ agg1, int N) {
  int v = blockIdx.x * 4 + (threadIdx.x >> 6);
  if (v >= N) return;
  int l = threadIdx.x & 63;
  const unsigned short* xbase = reinterpret_cast<const unsigned short*>(x8);
  unsigned t = xbase[(size_t)v * 64 + l];
  float a0 = d8(t & 0xffu), a1 = d8(t >> 8);
  int e0 = rowptr[v], e1 = rowptr[v + 1];
  int e = e0;
  for (; e + 4 <= e1; e += 4) {
    unsigned t0 = xbase[(size_t)csr[e] * 64 + l];
    unsigned t1 = xbase[(size_t)csr[e + 1] * 64 + l];
    unsigned t2 = xbase[(size_t)csr[e + 2] * 64 + l];
    unsigned t3 = xbase[(size_t)csr[e + 3] * 64 + l];
    a0 += d8(t0 & 0xffu) + d8(t1 & 0xffu) + d8(t2 & 0xffu) + d8(t3 & 0xffu);
    a1 += d8(t0 >> 8) + d8(t1 >> 8) + d8(t2 >> 8) + d8(t3 >> 8);
  }
  for (; e < e1; ++e) {
    unsigned tt = xbase[(size_t)csr[e] * 64 + l];
    a0 += d8(tt & 0xffu); a1 += d8(tt >> 8);
  }
  int cnt10[10] = {};
  for (int base = e0; base < e1; base += 64) {
    int ee = base + l;
    int id = (ee < e1) ? ids[csr[ee]] : -1;
#pragma unroll
    for (int k = 0; k < 10; ++k)
      cnt10[k] += (int)__popcll(__ballot(id == k));
  }
  int myid = ids[v];
  unsigned* row32 = reinterpret_cast<unsigned*>(agg1 + (size_t)v * K1);
  row32[l] = (unsigned)f2b(a0) | ((unsigned)f2b(a1) << 16);
  if (l < 16) {
    float v0 = 0.f, v1 = 0.f;
#pragma unroll
    for (int kk = 0; kk < 10; ++kk) {
      float cv = (float)(cnt10[kk] + (myid == kk ? 1 : 0));
      if (2 * l == kk) v0 = cv;
      if (2 * l + 1 == kk) v1 = cv;
    }
    row32[64 + l] = (unsigned)f2b(v0) | ((unsigned)f2b(v1) << 16);
  }
}

// ---------------- persistent-B pipelined bf16 MFMA GEMM ----------------
// grid=256 blocks x 512 thr. B staged once (XOR-swizzled), A streamed
// per 128-row tile, BK=32, 3 buffers, counted vmcnt(1).
// EPI 0: H = bf16 relu(acc+bias). EPI 1: H = fp8 raw acc (y = h@W2).
template <int KT, int BROW, int NT, int EPI>
__global__ __launch_bounds__(512, 1) void k_gemm(
    const unsigned short* __restrict__ A, const unsigned short* __restrict__ Bt,
    const float* __restrict__ bias, void* __restrict__ Hout, int M) {
  constexpr int ROWB = BROW * 2;
  __shared__ __align__(16) unsigned short b_s[HDIM * BROW];
  __shared__ __align__(16) unsigned short a_s[3 * 4096];

  const int tid = threadIdx.x;
  const int w = tid >> 6, l = tid & 63;
  const int wm = w >> 2, wn = w & 3;
  const int lr = l & 15, lq = l >> 4, lk = lq * 8;
  const int b = blockIdx.x;
  const int TT = (M + 127) >> 7;
  const int ntb = (TT > b) ? ((TT - b + 255) >> 8) : 0;
  const int total = ntb * NT;

  constexpr int BITERS = BROW / 16;
#pragma unroll
  for (int it = 0; it < BITERS; ++it) {
    int d = (it * 512 + tid) * 16;
    int n = d / ROWB;
    int inrow = d - n * ROWB;
    int u = inrow ^ ((n & 7) << 4);
    glds16(Bt + (size_t)n * BROW + (u >> 1), b_s + (size_t)(it * 512 + w * 64) * 8);
  }
  auto stageA = [&](int s) {
    int buf = s - (s / 3) * 3;
    int m0 = (b + (s / NT) * 256) << 7;
    int k0 = (s % NT) * 32;
    int d = tid * 16;
    int u = d ^ (((d >> 7) & 7) << 4);
    int r = ((u >> 7) << 1) | ((u >> 6) & 1);
    int k = (u >> 1) & 31;
    glds16(A + (size_t)(m0 + r) * KT + k0 + k, a_s + buf * 4096 + w * 512);
  };
  if (total > 0) stageA(0);
  if (total > 1) stageA(1);
  if (total > 1) { asm volatile("s_waitcnt vmcnt(1)" ::: "memory"); }
  else           { asm volatile("s_waitcnt vmcnt(0)" ::: "memory"); }
  __builtin_amdgcn_s_barrier();
  __builtin_amdgcn_sched_barrier(0);

  float bv[4];
  if constexpr (EPI == 0) {
#pragma unroll
    for (int nf = 0; nf < 4; ++nf) bv[nf] = bias[wn * 64 + nf * 16 + lr];
  }

  int aoff[4];
#pragma unroll
  for (int mf = 0; mf < 4; ++mf) {
    int R = wm * 64 + mf * 16 + lr;
    aoff[mf] = (((R >> 1) * 128 + (R & 1) * 64 + lk * 2) ^ (((R >> 1) & 7) << 4));
  }

  int s = 0;
  for (int ti = 0; ti < ntb; ++ti) {
    const int m0t = (b + ti * 256) << 7;
    f32x4 acc[4][4] = {};
    for (int ks = 0; ks < NT; ++ks, ++s) {
      const bool pre = (s + 2 < total);
      if (pre) stageA(s + 2);
      const char* ab = reinterpret_cast<const char*>(a_s) + (s - (s / 3) * 3) * 8192;
      bf16x8 af[4], bfr[4];
#pragma unroll
      for (int mf = 0; mf < 4; ++mf)
        af[mf] = *reinterpret_cast<const bf16x8*>(ab + aoff[mf]);
#pragma unroll
      for (int nf = 0; nf < 4; ++nf) {
        int n = wn * 64 + nf * 16 + lr;
        int bb = n * ROWB + (((ks * 32 + lk) * 2) ^ ((n & 7) << 4));
        bfr[nf] = *reinterpret_cast<const bf16x8*>(reinterpret_cast<const char*>(b_s) + bb);
      }
      __builtin_amdgcn_s_setprio(1);
#pragma unroll
      for (int mf = 0; mf < 4; ++mf)
#pragma unroll
        for (int nf = 0; nf < 4; ++nf)
          acc[mf][nf] = __builtin_amdgcn_mfma_f32_16x16x32_bf16(af[mf], bfr[nf], acc[mf][nf], 0, 0, 0);
      __builtin_amdgcn_s_setprio(0);
      if (pre) { asm volatile("s_waitcnt vmcnt(1)" ::: "memory"); }
      else     { asm volatile("s_waitcnt vmcnt(0)" ::: "memory"); }
      __builtin_amdgcn_s_barrier();
      __builtin_amdgcn_sched_barrier(0);
    }

#pragma unroll
    for (int mf = 0; mf < 4; ++mf)
#pragma unroll
      for (int q = 0; q < 4; ++q) {
        int grow = m0t + wm * 64 + mf * 16 + lq * 4 + q;
        if (grow < M) {
          size_t ro = (size_t)grow * HDIM + wn * 64 + lr;
          if constexpr (EPI == 0) {
            unsigned short* H = (unsigned short*)Hout;
#pragma unroll
            for (int nf = 0; nf < 4; ++nf) {
              float vv = acc[mf][nf][q] + bv[nf];
              H[ro + nf * 16] = f2b(vv > 0.f ? vv : 0.f);
            }
          } else {
            unsigned char* H8 = (unsigned char*)Hout;
#pragma unroll
            for (int nf = 0; nf < 4; ++nf)
              H8[ro + nf * 16] = (unsigned char)e8(acc[mf][nf][q]);
          }
        }
      }
  }
}

// ---------------- fused fp8 gather + relu + segment pool ----------------
// block = 128 nodes, 4 waves x 32 contiguous nodes. ysum_v = y_v + sum_N y_u;
// out[g] += relu(ysum_v + b2). Register accs flushed per segment to per-wave
// LDS slices (wave-uniform seg), cross-wave reduce, few global atomics.
__global__ __launch_bounds__(256) void k_gp(
    const unsigned char* __restrict__ y8, const int* __restrict__ bids,
    const int* __restrict__ rowptr, const int* __restrict__ csr,
    const float* __restrict__ b2, float* __restrict__ out, int N) {
  __shared__ float red[4][MAXS][HDIM];
  __shared__ int seg_l[128];
  __shared__ int gseg_l[128];
  __shared__ int wtot2[2];
  __shared__ int nseg_sh;
  const int tid = threadIdx.x;
  const int w = tid >> 6, l = tid & 63;
  const int v0 = blockIdx.x * 128;

  float* rz = &red[0][0][0];
  for (int i = tid; i < 4 * MAXS * HDIM; i += 256) rz[i] = 0.f;

  if (tid < 128) {
    int i0 = v0 + tid; i0 = i0 < N ? i0 : N - 1;
    int i1 = v0 + tid - 1; i1 = i1 < N ? i1 : N - 1; i1 = i1 > 0 ? i1 : 0;
    int g = bids[i0];
    bool bnd = (tid > 0) && (g != bids[i1]);
    unsigned long long mb = __ballot(bnd);
    int lane = tid & 63;
    int incl = (int)__popcll(mb & (~0ULL >> (63 - lane)));
    seg_l[tid] = incl;
    if (lane == 63) wtot2[tid >> 6] = incl;
  }
  __syncthreads();
  if (tid < 128) {
    int sfin = seg_l[tid] + ((tid >= 64) ? wtot2[0] : 0);
    seg_l[tid] = sfin;
    int i0 = v0 + tid; i0 = i0 < N ? i0 : N - 1;
    int i1 = v0 + tid - 1; i1 = i1 < N ? i1 : N - 1; i1 = i1 > 0 ? i1 : 0;
    int g = bids[i0];
    if (tid == 0 || g != bids[i1]) gseg_l[sfin] = g;
    if (tid == 127) nseg_sh = sfin + 1;
  }
  __syncthreads();
  const int nseg = nseg_sh;
  const bool fb = (nseg > MAXS);   // pathological fallback (block-uniform)

  float bv0 = b2[l * 4 + 0], bv1 = b2[l * 4 + 1];
  float bv2 = b2[l * 4 + 2], bv3 = b2[l * 4 + 3];
  const unsigned* yb = reinterpret_cast<const unsigned*>(y8);

  float a0 = 0.f, a1 = 0.f, a2 = 0.f, a3 = 0.f;
  int cur = seg_l[w * 32];
  for (int i = 0; i < 32; ++i) {
    int idx = w * 32 + i;
    int v = v0 + idx;
    if (v >= N) break;
    int sg = seg_l[idx];
    if (sg != cur) {                       // wave-uniform flush
      if (!fb) {
        float* rp = &red[w][cur][l * 4];
        rp[0] += a0; rp[1] += a1; rp[2] += a2; rp[3] += a3;
      }
      a0 = a1 = a2 = a3 = 0.f;
      cur = sg;
    }
    unsigned t = yb[(size_t)v * 64 + l];
    float s0 = d8(t & 0xffu), s1 = d8((t >> 8) & 0xffu);
    float s2 = d8((t >> 16) & 0xffu), s3 = d8(t >> 24);
    int e0 = rowptr[v], e1 = rowptr[v + 1];
    int e = e0;
    for (; e + 4 <= e1; e += 4) {
      unsigned t0 = yb[(size_t)csr[e] * 64 + l];
      unsigned t1 = yb[(size_t)csr[e + 1] * 64 + l];
      unsigned t2 = yb[(size_t)csr[e + 2] * 64 + l];
      unsigned t3 = yb[(size_t)csr[e + 3] * 64 + l];
      s0 += d8(t0 & 0xffu) + d8(t1 & 0xffu) + d8(t2 & 0xffu) + d8(t3 & 0xffu);
      s1 += d8((t0 >> 8) & 0xffu) + d8((t1 >> 8) & 0xffu) + d8((t2 >> 8) & 0xffu) + d8((t3 >> 8) & 0xffu);
      s2 += d8((t0 >> 16) & 0xffu) + d8((t1 >> 16) & 0xffu) + d8((t2 >> 16) & 0xffu) + d8((t3 >> 16) & 0xffu);
      s3 += d8(t0 >> 24) + d8(t1 >> 24) + d8(t2 >> 24) + d8(t3 >> 24);
    }
    for (; e < e1; ++e) {
      unsigned tt = yb[(size_t)csr[e] * 64 + l];
      s0 += d8(tt & 0xffu); s1 += d8((tt >> 8) & 0xffu);
      s2 += d8((tt >> 16) & 0xffu); s3 += d8(tt >> 24);
    }
    s0 = fmaxf(s0 + bv0, 0.f); s1 = fmaxf(s1 + bv1, 0.f);
    s2 = fmaxf(s2 + bv2, 0.f); s3 = fmaxf(s3 + bv3, 0.f);
    if (fb) {
      int g = bids[v];
      float* op = out + (size_t)g * HDIM + l * 4;
      if (s0 > 0.f) atomicAdd(&op[0], s0);
      if (s1 > 0.f) atomicAdd(&op[1], s1);
      if (s2 > 0.f) atomicAdd(&op[2], s2);
      if (s3 > 0.f) atomicAdd(&op[3], s3);
    } else {
      a0 += s0; a1 += s1; a2 += s2; a3 += s3;
    }
  }
  if (!fb) {
    float* rp = &red[w][cur][l * 4];
    rp[0] += a0; rp[1] += a1; rp[2] += a2; rp[3] += a3;
  }
  __syncthreads();
  if (!fb) {
    for (int sg = 0; sg < nseg; ++sg) {
      float val = red[0][sg][tid] + red[1][sg][tid] + red[2][sg][tid] + red[3][sg][tid];
      if (val != 0.f) atomicAdd(&out[(size_t)gseg_l[sg] * HDIM + tid], val);
    }
  }
}

extern "C" void kernel_launch(void* const* d_in, const int* in_sizes, int n_in,
                              void* d_out, int out_size, void* d_ws, size_t ws_size,
                              hipStream_t stream) {
  const float* x    = (const float*)d_in[0];
  const int*   ei   = (const int*)d_in[1];
  const int*   bids = (const int*)d_in[2];
  const float* W1   = (const float*)d_in[3];
  const float* b1   = (const float*)d_in[4];
  const float* W2   = (const float*)d_in[5];
  const float* b2   = (const float*)d_in[6];
  float* out = (float*)d_out;

  const int N = in_sizes[2];
  const int E = in_sizes[1] / 2;
  const int* src = ei;
  const int* dst = ei + E;

  char* ws = (char*)d_ws;
  size_t off = 0;
  auto alloc = [&](size_t bytes) {
    size_t o = off;
    off = (off + bytes + 255) & ~(size_t)255;
    return o;
  };
  float* r      = (float*)(ws + alloc((size_t)N * 4));
  int*   ids    = (int*)(ws + alloc((size_t)N * 4));
  int*   start  = (int*)(ws + alloc((size_t)NGRAPH * 4));
  int*   cnt    = (int*)(ws + alloc((size_t)NGRAPH * 4));
  int*   deg    = (int*)(ws + alloc((size_t)N * 4));
  int*   fill   = (int*)(ws + alloc((size_t)N * 4));
  int*   rowptr = (int*)(ws + alloc((size_t)(N + 1) * 4));
  int*   bsum   = (int*)(ws + alloc(512 * 4));
  int*   csr    = (int*)(ws + alloc((size_t)E * 4));
  unsigned short* Wpt = (unsigned short*)(ws + alloc((size_t)HDIM * B1ROW * 2));
  unsigned short* W2t = (unsigned short*)(ws + alloc((size_t)HDIM * HDIM * 2));
  unsigned char*  x8  = (unsigned char*)(ws + alloc((size_t)N * D_IN));
  // +128 rows padding: GEMM staging reads up to the 128-row tile past M
  unsigned short* agg1 = (unsigned short*)(ws + alloc((size_t)(N + 128) * K1 * 2));
  unsigned short* h    = (unsigned short*)(ws + alloc((size_t)(N + 128) * HDIM * 2));
  unsigned char*  y8   = (unsigned char*)(ws + alloc((size_t)(N + 128) * HDIM));
  (void)ws_size;

  // cnt/deg/fill contiguous: single memset over the span
  size_t zspan = (size_t)((char*)(fill + N) - (char*)cnt);
  hipMemsetAsync(cnt, 0, zspan, stream);
  hipMemsetAsync(out, 0, (size_t)out_size * 4, stream);

  const int nb = (N + 255) / 256;
  const int n8 = N * 16;
  const int xbb = (n8 + 255) / 256;
  const int wb = (HDIM * B1ROW + HDIM * HDIM + 255) / 256;

  k_prep2<<<(E + 255) / 256, 256, 0, stream>>>(bids, dst, r, start, cnt, deg, N, E);
  k_pre<<<xbb + wb, 256, 0, stream>>>(x, W1, W2, x8, Wpt, W2t, n8, xbb);
  k_scan1<<<nb, 256, 0, stream>>>(deg, rowptr, bsum, N);
  k_scan2<<<1, 512, 0, stream>>>(bsum, nb);
  k_scan3<<<nb, 256, 0, stream>>>(rowptr, bsum, N, E);
  k_scatter<<<(E + 255) / 256, 256, 0, stream>>>(src, dst, rowptr, fill, csr, E);
  k_rank<<<NGRAPH, 64, 0, stream>>>(r, start, cnt, ids);
  k_agg1<<<(N + 3) / 4, 256, 0, stream>>>(x8, ids, rowptr, csr, agg1, N);

  k_gemm<K1, B1ROW, 5, 0><<<256, 512, 0, stream>>>(agg1, Wpt, b1, (void*)h, N);
  k_gemm<HDIM, HDIM, 8, 1><<<256, 512, 0, stream>>>(h, W2t, nullptr, (void*)y8, N);

  k_gp<<<(N + 127) / 128, 256, 0, stream>>>(y8, bids, rowptr, csr, b2, out, N);
}

// Round 8
// 372.803 us; speedup vs baseline: 1.1365x; 1.1365x over previous
//
#include <hip/hip_runtime.h>
#include <hip/hip_bf16.h>
#include <stdint.h>

// RPGNN: threefry ranks -> CSR -> fp8 gather-agg -> persistent-B pipelined
// bf16 MFMA GEMMs -> y=h@W2 (fp8 out) -> fused fp8-gather+relu+segment-pool.
// Layer2 linearity: (h + sum_N h) @ W2 = y_v + sum_N y_u, y = h@W2.
// fp8 encode/decode via gfx950 HW converters (v_cvt_pk_*_fp8).

#define D_IN   128
#define KRAW   138
#define K1     160   // A row stride, layer 1
#define B1ROW  192   // B padded row (elems) layer 1
#define HDIM   256
#define NGRAPH 2000

typedef __bf16 bf16x8 __attribute__((ext_vector_type(8)));
typedef float  f32x4  __attribute__((ext_vector_type(4)));
typedef float  f32x2  __attribute__((ext_vector_type(2)));

__device__ __forceinline__ unsigned short f2b(float f) {
  __hip_bfloat16 h = __float2bfloat16(f);
  return __builtin_bit_cast(unsigned short, h);
}

// ---- OCP e4m3 encode/decode: HW converters with manual fallback ----
#if __has_builtin(__builtin_amdgcn_cvt_pk_f32_fp8) && __has_builtin(__builtin_amdgcn_cvt_pk_fp8_f32)
#define HW_FP8 1
#endif

__device__ __forceinline__ unsigned e8_sw(float f) {
  unsigned u = __float_as_uint(f);
  unsigned s = (u >> 24) & 0x80u;
  float a = fabsf(f);
  if (!(a >= 0.015625f)) return s;
  a = fminf(a, 448.f);
  unsigned b = __float_as_uint(a);
  b += 0x0007FFFFu + ((b >> 20) & 1u);
  unsigned e = (b >> 23) - 120u;
  unsigned m = (b >> 20) & 7u;
  return s | (e << 3) | m;
}
__device__ __forceinline__ float d8_sw(unsigned byte) {
  unsigned m = byte & 0x7fu;
  unsigned bits = (0x3C000000u + (m << 20)) | ((byte & 0x80u) << 24);
  return m ? __uint_as_float(bits) : 0.f;
}

template <bool HI>
__device__ __forceinline__ f32x2 dec2(unsigned w) {
#ifdef HW_FP8
  return __builtin_amdgcn_cvt_pk_f32_fp8((int)w, HI);
#else
  unsigned hw = HI ? (w >> 16) : (w & 0xffffu);
  f32x2 r; r.x = d8_sw(hw & 0xffu); r.y = d8_sw(hw >> 8); return r;
#endif
}
template <bool HI>
__device__ __forceinline__ int enc2(float a, float b, int old) {
#ifdef HW_FP8
  return __builtin_amdgcn_cvt_pk_fp8_f32(a, b, old, HI);
#else
  unsigned p = e8_sw(a) | (e8_sw(b) << 8);
  return HI ? ((old & 0xffff) | (int)(p << 16)) : ((int)(old & 0xffff0000u) | (int)p);
#endif
}
__device__ __forceinline__ unsigned char enc1(float v) {
#ifdef HW_FP8
  // both bytes hold v -> byte-order robust
  return (unsigned char)(__builtin_amdgcn_cvt_pk_fp8_f32(v, v, 0, false) & 0xff);
#else
  return (unsigned char)e8_sw(v);
#endif
}

__device__ __forceinline__ void glds16(const unsigned short* g, unsigned short* l) {
  __builtin_amdgcn_global_load_lds(
      (const __attribute__((address_space(1))) unsigned int*)g,
      (__attribute__((address_space(3))) unsigned int*)l, 16, 0, 0);
}

// ---------------- threefry2x32 (bit-exact JAX replica) ----------------
__device__ __forceinline__ unsigned rotl32(unsigned x, int r) {
  return (x << r) | (x >> (32 - r));
}
__device__ __forceinline__ void threefry2x32(unsigned k0, unsigned k1,
                                             unsigned x0, unsigned x1,
                                             unsigned& o0, unsigned& o1) {
  unsigned ks2 = k0 ^ k1 ^ 0x1BD11BDAu;
  unsigned ks[3] = {k0, k1, ks2};
  x0 += ks[0]; x1 += ks[1];
  const int rotA[4] = {13, 15, 26, 6};
  const int rotB[4] = {17, 29, 16, 24};
#pragma unroll
  for (int i = 0; i < 5; ++i) {
    const int* rot = (i & 1) ? rotB : rotA;
#pragma unroll
    for (int j = 0; j < 4; ++j) {
      x0 += x1; x1 = rotl32(x1, rot[j]); x1 ^= x0;
    }
    x0 += ks[(i + 1) % 3];
    x1 += ks[(i + 2) % 3] + (unsigned)(i + 1);
  }
  o0 = x0; o1 = x1;
}

__global__ void k_prep2(const int* __restrict__ bids, const int* __restrict__ dst,
                        float* __restrict__ r, int* __restrict__ start,
                        int* __restrict__ cnt, int* __restrict__ deg, int N, int E) {
  int i = blockIdx.x * blockDim.x + threadIdx.x;
  if (i < E) atomicAdd(&deg[dst[i]], 1);
  if (i >= N) return;
  int half = N >> 1;
  if (i < half) {
    unsigned fk0, fk1;
    threefry2x32(0u, 42u, 0u, 0u, fk0, fk1);          // fold_in(key(42), 0)
    unsigned b0, b1v;
    threefry2x32(fk0, fk1, (unsigned)i, (unsigned)(i + half), b0, b1v);
    r[i]        = __uint_as_float((b0  >> 9) | 0x3f800000u) - 1.0f;
    r[i + half] = __uint_as_float((b1v >> 9) | 0x3f800000u) - 1.0f;
  }
  int g = bids[i];
  if (i == 0 || bids[i - 1] != g) start[g] = i;
  atomicAdd(&cnt[g], 1);
}

// rank within graph under key = float(g)+r, stable tie-break on index
__global__ void k_rank(const float* __restrict__ r, const int* __restrict__ start,
                       const int* __restrict__ cnt, int* __restrict__ ids) {
  int g = blockIdx.x;
  int st = start[g], n = cnt[g];
  if (n <= 0) return;
  float gf = (float)g;
  for (int t = threadIdx.x; t < n; t += blockDim.x) {
    int v = st + t;
    float kv = gf + r[v];
    int c = 0;
    for (int u0 = 0; u0 < n; ++u0) {
      int u = st + u0;
      float ku = gf + r[u];
      c += (int)((ku < kv) | ((ku == kv) & (u < v)));
    }
    ids[v] = c % 10;
  }
}

// ---------------- CSR build ----------------
__global__ void k_scan1(const int* __restrict__ deg, int* __restrict__ rowptr,
                        int* __restrict__ bsum, int N) {
  __shared__ int buf[256];
  int tid = threadIdx.x;
  int i = blockIdx.x * 256 + tid;
  int v = (i < N) ? deg[i] : 0;
  buf[tid] = v;
  __syncthreads();
  for (int off = 1; off < 256; off <<= 1) {
    int t = (tid >= off) ? buf[tid - off] : 0;
    __syncthreads();
    buf[tid] += t;
    __syncthreads();
  }
  if (i < N) rowptr[i] = buf[tid] - v;
  if (tid == 255) bsum[blockIdx.x] = buf[255];
}

__global__ void k_scan2(int* __restrict__ bsum, int nb) {
  __shared__ int buf[512];
  int tid = threadIdx.x;
  int v = (tid < nb) ? bsum[tid] : 0;
  buf[tid] = v;
  __syncthreads();
  for (int off = 1; off < 512; off <<= 1) {
    int t = (tid >= off) ? buf[tid - off] : 0;
    __syncthreads();
    buf[tid] += t;
    __syncthreads();
  }
  if (tid < nb) bsum[tid] = buf[tid] - v;
}

__global__ void k_scan3(int* __restrict__ rowptr, const int* __restrict__ bsum,
                        int N, int E) {
  int i = blockIdx.x * 256 + threadIdx.x;
  if (i < N) rowptr[i] += bsum[blockIdx.x];
  if (i == 0) rowptr[N] = E;
}

__global__ void k_scatter(const int* __restrict__ src, const int* __restrict__ dst,
                          const int* __restrict__ rowptr, int* __restrict__ fill,
                          int* __restrict__ csr, int E) {
  int e = blockIdx.x * 256 + threadIdx.x;
  if (e >= E) return;
  int d = dst[e];
  int pos = rowptr[d] + atomicAdd(&fill[d], 1);
  csr[pos] = src[e];
}

// ---------------- x->fp8 + weight prep (merged) ----------------
__global__ void k_pre(const float* __restrict__ x, const float* __restrict__ W1,
                      const float* __restrict__ W2, unsigned char* __restrict__ x8,
                      unsigned short* __restrict__ Wpt, unsigned short* __restrict__ W2t,
                      int n8, int xbb) {
  int bid = blockIdx.x;
  int tid = threadIdx.x;
  if (bid < xbb) {
    int i = bid * 256 + tid;
    if (i >= n8) return;
    const float4* xp = reinterpret_cast<const float4*>(x) + (size_t)i * 2;
    float4 v0 = xp[0], v1 = xp[1];
    uint2 o;
    o.x = (unsigned)enc2<true>(v0.z, v0.w, enc2<false>(v0.x, v0.y, 0));
    o.y = (unsigned)enc2<true>(v1.z, v1.w, enc2<false>(v1.x, v1.y, 0));
    reinterpret_cast<uint2*>(x8)[i] = o;
  } else {
    int j = (bid - xbb) * 256 + tid;
    if (j < HDIM * B1ROW) {
      int n = j / B1ROW, k = j % B1ROW;
      Wpt[j] = f2b(k < KRAW ? W1[k * HDIM + n] : 0.f);
    } else {
      int j2 = j - HDIM * B1ROW;
      if (j2 < HDIM * HDIM) {
        int n = j2 >> 8, k = j2 & 255;
        W2t[j2] = f2b(W2[k * HDIM + n]);
      }
    }
  }
}

// ---------------- layer-1 aggregation (wave/node, fp8 gather) ----------------
__global__ void k_agg1(const unsigned char* __restrict__ x8, const int* __restrict__ ids,
                       const int* __restrict__ rowptr, const int* __restrict__ csr,
                       unsigned short* __restrict__ agg1, int N) {
  int v = blockIdx.x * 4 + (threadIdx.x >> 6);
  if (v >= N) return;
  int l = threadIdx.x & 63;
  const unsigned short* xbase = reinterpret_cast<const unsigned short*>(x8);
  f32x2 p = dec2<false>((unsigned)xbase[(size_t)v * 64 + l]);
  float a0 = p.x, a1 = p.y;
  int e0 = rowptr[v], e1 = rowptr[v + 1];
  int e = e0;
  for (; e + 4 <= e1; e += 4) {
    unsigned t0 = xbase[(size_t)csr[e] * 64 + l];
    unsigned t1 = xbase[(size_t)csr[e + 1] * 64 + l];
    unsigned t2 = xbase[(size_t)csr[e + 2] * 64 + l];
    unsigned t3 = xbase[(size_t)csr[e + 3] * 64 + l];
    f32x2 q0 = dec2<false>(t0), q1 = dec2<false>(t1);
    f32x2 q2 = dec2<false>(t2), q3 = dec2<false>(t3);
    a0 += q0.x + q1.x + q2.x + q3.x;
    a1 += q0.y + q1.y + q2.y + q3.y;
  }
  for (; e < e1; ++e) {
    f32x2 q = dec2<false>((unsigned)xbase[(size_t)csr[e] * 64 + l]);
    a0 += q.x; a1 += q.y;
  }
  int cnt10[10] = {};
  for (int base = e0; base < e1; base += 64) {
    int ee = base + l;
    int id = (ee < e1) ? ids[csr[ee]] : -1;
#pragma unroll
    for (int k = 0; k < 10; ++k)
      cnt10[k] += (int)__popcll(__ballot(id == k));
  }
  int myid = ids[v];
  unsigned* row32 = reinterpret_cast<unsigned*>(agg1 + (size_t)v * K1);
  row32[l] = (unsigned)f2b(a0) | ((unsigned)f2b(a1) << 16);
  if (l < 16) {
    float v0 = 0.f, v1 = 0.f;
#pragma unroll
    for (int kk = 0; kk < 10; ++kk) {
      float cv = (float)(cnt10[kk] + (myid == kk ? 1 : 0));
      if (2 * l == kk) v0 = cv;
      if (2 * l + 1 == kk) v1 = cv;
    }
    row32[64 + l] = (unsigned)f2b(v0) | ((unsigned)f2b(v1) << 16);
  }
}

// ---------------- persistent-B pipelined bf16 MFMA GEMM ----------------
// grid=256 blocks x 512 thr. B staged once (XOR-swizzled), A streamed
// per 128-row tile, BK=32, 3 buffers, counted vmcnt(1).
// EPI 0: H = bf16 relu(acc+bias). EPI 1: H = fp8 raw acc (y = h@W2).
template <int KT, int BROW, int NT, int EPI>
__global__ __launch_bounds__(512, 1) void k_gemm(
    const unsigned short* __restrict__ A, const unsigned short* __restrict__ Bt,
    const float* __restrict__ bias, void* __restrict__ Hout, int M) {
  constexpr int ROWB = BROW * 2;
  __shared__ __align__(16) unsigned short b_s[HDIM * BROW];
  __shared__ __align__(16) unsigned short a_s[3 * 4096];

  const int tid = threadIdx.x;
  const int w = tid >> 6, l = tid & 63;
  const int wm = w >> 2, wn = w & 3;
  const int lr = l & 15, lq = l >> 4, lk = lq * 8;
  const int b = blockIdx.x;
  const int TT = (M + 127) >> 7;
  const int ntb = (TT > b) ? ((TT - b + 255) >> 8) : 0;
  const int total = ntb * NT;

  constexpr int BITERS = BROW / 16;
#pragma unroll
  for (int it = 0; it < BITERS; ++it) {
    int d = (it * 512 + tid) * 16;
    int n = d / ROWB;
    int inrow = d - n * ROWB;
    int u = inrow ^ ((n & 7) << 4);
    glds16(Bt + (size_t)n * BROW + (u >> 1), b_s + (size_t)(it * 512 + w * 64) * 8);
  }
  auto stageA = [&](int s) {
    int buf = s - (s / 3) * 3;
    int m0 = (b + (s / NT) * 256) << 7;
    int k0 = (s % NT) * 32;
    int d = tid * 16;
    int u = d ^ (((d >> 7) & 7) << 4);
    int r = ((u >> 7) << 1) | ((u >> 6) & 1);
    int k = (u >> 1) & 31;
    glds16(A + (size_t)(m0 + r) * KT + k0 + k, a_s + buf * 4096 + w * 512);
  };
  if (total > 0) stageA(0);
  if (total > 1) stageA(1);
  if (total > 1) { asm volatile("s_waitcnt vmcnt(1)" ::: "memory"); }
  else           { asm volatile("s_waitcnt vmcnt(0)" ::: "memory"); }
  __builtin_amdgcn_s_barrier();
  __builtin_amdgcn_sched_barrier(0);

  float bv[4];
  if constexpr (EPI == 0) {
#pragma unroll
    for (int nf = 0; nf < 4; ++nf) bv[nf] = bias[wn * 64 + nf * 16 + lr];
  }

  int aoff[4];
#pragma unroll
  for (int mf = 0; mf < 4; ++mf) {
    int R = wm * 64 + mf * 16 + lr;
    aoff[mf] = (((R >> 1) * 128 + (R & 1) * 64 + lk * 2) ^ (((R >> 1) & 7) << 4));
  }

  int s = 0;
  for (int ti = 0; ti < ntb; ++ti) {
    const int m0t = (b + ti * 256) << 7;
    f32x4 acc[4][4] = {};
    for (int ks = 0; ks < NT; ++ks, ++s) {
      const bool pre = (s + 2 < total);
      if (pre) stageA(s + 2);
      const char* ab = reinterpret_cast<const char*>(a_s) + (s - (s / 3) * 3) * 8192;
      bf16x8 af[4], bfr[4];
#pragma unroll
      for (int mf = 0; mf < 4; ++mf)
        af[mf] = *reinterpret_cast<const bf16x8*>(ab + aoff[mf]);
#pragma unroll
      for (int nf = 0; nf < 4; ++nf) {
        int n = wn * 64 + nf * 16 + lr;
        int bb = n * ROWB + (((ks * 32 + lk) * 2) ^ ((n & 7) << 4));
        bfr[nf] = *reinterpret_cast<const bf16x8*>(reinterpret_cast<const char*>(b_s) + bb);
      }
      __builtin_amdgcn_s_setprio(1);
#pragma unroll
      for (int mf = 0; mf < 4; ++mf)
#pragma unroll
        for (int nf = 0; nf < 4; ++nf)
          acc[mf][nf] = __builtin_amdgcn_mfma_f32_16x16x32_bf16(af[mf], bfr[nf], acc[mf][nf], 0, 0, 0);
      __builtin_amdgcn_s_setprio(0);
      if (pre) { asm volatile("s_waitcnt vmcnt(1)" ::: "memory"); }
      else     { asm volatile("s_waitcnt vmcnt(0)" ::: "memory"); }
      __builtin_amdgcn_s_barrier();
      __builtin_amdgcn_sched_barrier(0);
    }

#pragma unroll
    for (int mf = 0; mf < 4; ++mf)
#pragma unroll
      for (int q = 0; q < 4; ++q) {
        int grow = m0t + wm * 64 + mf * 16 + lq * 4 + q;
        if (grow < M) {
          size_t ro = (size_t)grow * HDIM + wn * 64 + lr;
          if constexpr (EPI == 0) {
            unsigned short* H = (unsigned short*)Hout;
#pragma unroll
            for (int nf = 0; nf < 4; ++nf) {
              float vv = acc[mf][nf][q] + bv[nf];
              H[ro + nf * 16] = f2b(vv > 0.f ? vv : 0.f);
            }
          } else {
            unsigned char* H8 = (unsigned char*)Hout;
#pragma unroll
            for (int nf = 0; nf < 4; ++nf)
              H8[ro + nf * 16] = enc1(acc[mf][nf][q]);
          }
        }
      }
  }
}

// ---------------- fused fp8 gather + relu + pool (wave per 8 nodes) ----------------
// ysum_v = y_v + sum_N y_u; out[g] += relu(ysum_v + b2). Register acc across
// consecutive nodes; flush to global atomics on graph boundary (wave-uniform).
__global__ __launch_bounds__(256) void k_gp(
    const unsigned char* __restrict__ y8, const int* __restrict__ bids,
    const int* __restrict__ rowptr, const int* __restrict__ csr,
    const float* __restrict__ b2, float* __restrict__ out, int N) {
  const int wid = blockIdx.x * 4 + (threadIdx.x >> 6);
  const int l = threadIdx.x & 63;
  int v0 = wid * 8;
  if (v0 >= N) return;
  int vend = (v0 + 8 < N) ? v0 + 8 : N;
  const float4 bv = reinterpret_cast<const float4*>(b2)[l];
  const unsigned* yb = reinterpret_cast<const unsigned*>(y8);

  float a0 = 0.f, a1 = 0.f, a2 = 0.f, a3 = 0.f;
  int gcur = bids[v0];
  for (int v = v0; v < vend; ++v) {
    int g = bids[v];
    if (g != gcur) {                               // wave-uniform flush
      float* op = out + (size_t)gcur * HDIM + l * 4;
      atomicAdd(&op[0], a0); atomicAdd(&op[1], a1);
      atomicAdd(&op[2], a2); atomicAdd(&op[3], a3);
      a0 = a1 = a2 = a3 = 0.f;
      gcur = g;
    }
    unsigned t = yb[(size_t)v * 64 + l];
    f32x2 p0 = dec2<false>(t), p1 = dec2<true>(t);
    float s0 = p0.x, s1 = p0.y, s2 = p1.x, s3 = p1.y;
    int e0 = rowptr[v], e1 = rowptr[v + 1];
    int e = e0;
    for (; e + 4 <= e1; e += 4) {
      unsigned t0 = yb[(size_t)csr[e] * 64 + l];
      unsigned t1 = yb[(size_t)csr[e + 1] * 64 + l];
      unsigned t2 = yb[(size_t)csr[e + 2] * 64 + l];
      unsigned t3 = yb[(size_t)csr[e + 3] * 64 + l];
      f32x2 q;
      q = dec2<false>(t0); s0 += q.x; s1 += q.y;
      q = dec2<true>(t0);  s2 += q.x; s3 += q.y;
      q = dec2<false>(t1); s0 += q.x; s1 += q.y;
      q = dec2<true>(t1);  s2 += q.x; s3 += q.y;
      q = dec2<false>(t2); s0 += q.x; s1 += q.y;
      q = dec2<true>(t2);  s2 += q.x; s3 += q.y;
      q = dec2<false>(t3); s0 += q.x; s1 += q.y;
      q = dec2<true>(t3);  s2 += q.x; s3 += q.y;
    }
    for (; e < e1; ++e) {
      unsigned tt = yb[(size_t)csr[e] * 64 + l];
      f32x2 q;
      q = dec2<false>(tt); s0 += q.x; s1 += q.y;
      q = dec2<true>(tt);  s2 += q.x; s3 += q.y;
    }
    a0 += fmaxf(s0 + bv.x, 0.f);
    a1 += fmaxf(s1 + bv.y, 0.f);
    a2 += fmaxf(s2 + bv.z, 0.f);
    a3 += fmaxf(s3 + bv.w, 0.f);
  }
  float* op = out + (size_t)gcur * HDIM + l * 4;
  atomicAdd(&op[0], a0); atomicAdd(&op[1], a1);
  atomicAdd(&op[2], a2); atomicAdd(&op[3], a3);
}

extern "C" void kernel_launch(void* const* d_in, const int* in_sizes, int n_in,
                              void* d_out, int out_size, void* d_ws, size_t ws_size,
                              hipStream_t stream) {
  const float* x    = (const float*)d_in[0];
  const int*   ei   = (const int*)d_in[1];
  const int*   bids = (const int*)d_in[2];
  const float* W1   = (const float*)d_in[3];
  const float* b1   = (const float*)d_in[4];
  const float* W2   = (const float*)d_in[5];
  const float* b2   = (const float*)d_in[6];
  float* out = (float*)d_out;

  const int N = in_sizes[2];
  const int E = in_sizes[1] / 2;
  const int* src = ei;
  const int* dst = ei + E;

  char* ws = (char*)d_ws;
  size_t off = 0;
  auto alloc = [&](size_t bytes) {
    size_t o = off;
    off = (off + bytes + 255) & ~(size_t)255;
    return o;
  };
  float* r      = (float*)(ws + alloc((size_t)N * 4));
  int*   ids    = (int*)(ws + alloc((size_t)N * 4));
  int*   start  = (int*)(ws + alloc((size_t)NGRAPH * 4));
  int*   cnt    = (int*)(ws + alloc((size_t)NGRAPH * 4));
  int*   deg    = (int*)(ws + alloc((size_t)N * 4));
  int*   fill   = (int*)(ws + alloc((size_t)N * 4));
  int*   rowptr = (int*)(ws + alloc((size_t)(N + 1) * 4));
  int*   bsum   = (int*)(ws + alloc(512 * 4));
  int*   csr    = (int*)(ws + alloc((size_t)E * 4));
  unsigned short* Wpt = (unsigned short*)(ws + alloc((size_t)HDIM * B1ROW * 2));
  unsigned short* W2t = (unsigned short*)(ws + alloc((size_t)HDIM * HDIM * 2));
  unsigned char*  x8  = (unsigned char*)(ws + alloc((size_t)N * D_IN));
  // +128 rows padding: GEMM staging reads up to the 128-row tile past M
  unsigned short* agg1 = (unsigned short*)(ws + alloc((size_t)(N + 128) * K1 * 2));
  unsigned short* h    = (unsigned short*)(ws + alloc((size_t)(N + 128) * HDIM * 2));
  unsigned char*  y8   = (unsigned char*)(ws + alloc((size_t)(N + 128) * HDIM));
  (void)ws_size;

  // cnt/deg/fill contiguous: single memset over the span
  size_t zspan = (size_t)((char*)(fill + N) - (char*)cnt);
  hipMemsetAsync(cnt, 0, zspan, stream);
  hipMemsetAsync(out, 0, (size_t)out_size * 4, stream);

  const int nb = (N + 255) / 256;
  const int n8 = N * 16;
  const int xbb = (n8 + 255) / 256;
  const int wb = (HDIM * B1ROW + HDIM * HDIM + 255) / 256;

  k_prep2<<<(E + 255) / 256, 256, 0, stream>>>(bids, dst, r, start, cnt, deg, N, E);
  k_pre<<<xbb + wb, 256, 0, stream>>>(x, W1, W2, x8, Wpt, W2t, n8, xbb);
  k_scan1<<<nb, 256, 0, stream>>>(deg, rowptr, bsum, N);
  k_scan2<<<1, 512, 0, stream>>>(bsum, nb);
  k_scan3<<<nb, 256, 0, stream>>>(rowptr, bsum, N, E);
  k_scatter<<<(E + 255) / 256, 256, 0, stream>>>(src, dst, rowptr, fill, csr, E);
  k_rank<<<NGRAPH, 64, 0, stream>>>(r, start, cnt, ids);
  k_agg1<<<(N + 3) / 4, 256, 0, stream>>>(x8, ids, rowptr, csr, agg1, N);

  k_gemm<K1, B1ROW, 5, 0><<<256, 512, 0, stream>>>(agg1, Wpt, b1, (void*)h, N);
  k_gemm<HDIM, HDIM, 8, 1><<<256, 512, 0, stream>>>(h, W2t, nullptr, (void*)y8, N);

  k_gp<<<(N + 31) / 32, 256, 0, stream>>>(y8, bids, rowptr, csr, b2, out, N);
}